// Round 9
// baseline (3480.684 us; speedup 1.0000x reference)
//
#include <hip/hip_runtime.h>
#include <hip/hip_bf16.h>

#define HID 16
#define NGRAPH 1000
#define NEG_SLOPE 0.2f
#define EPS_GN 1e-5f
#define BSH 10              // bucket shift: 1024 dsts per bucket
#define BS 1024             // bucket span (power of 2)
#define KEYS 8192           // BS * 8 slices
#define NBMAX 2048
#define CHK 4096            // edges per scatter chunk
#define NSLICE 8            // h slices of 64k nodes (2MB bf16-packed) -> per-XCD L2 resident

typedef __hip_bfloat16 bf16;

static __device__ __forceinline__ float b2f(bf16 v) { return __bfloat162float(v); }

// pack two floats into one u32 holding two RNE-rounded bf16s (a=low, b=high)
static __device__ __forceinline__ unsigned int pack2(float a, float b) {
    unsigned int ia = __float_as_uint(a);
    unsigned int ib = __float_as_uint(b);
    ia += 0x7FFFu + ((ia >> 16) & 1u);
    ib += 0x7FFFu + ((ib >> 16) & 1u);
    return (ia >> 16) | (ib & 0xFFFF0000u);
}

// acc[0..15] += p * bf16row(ra,rb)
static __device__ __forceinline__ void fma_row(const uint4 ra, const uint4 rb, float p,
                                               float* __restrict__ acc) {
    unsigned int us[8] = {ra.x, ra.y, ra.z, ra.w, rb.x, rb.y, rb.z, rb.w};
#pragma unroll
    for (int q = 0; q < 8; ++q) {
        float lo = __uint_as_float(us[q] << 16);
        float hi = __uint_as_float(us[q] & 0xFFFF0000u);
        acc[2 * q]     = fmaf(p, lo, acc[2 * q]);
        acc[2 * q + 1] = fmaf(p, hi, acc[2 * q + 1]);
    }
}

struct PtrPack { const void* src[30]; int cnt[30]; int dstoff[30]; int n; };

// ---------------- dtype detection + param conversion (single block) ----------------
__global__ void detect_cvt(const void* x, const void* ei, int* flags, PtrPack pk,
                           float* __restrict__ dst) {
    __shared__ int cbf, czero;
    __shared__ int isbS;
    int t = threadIdx.x;
    if (t == 0) { cbf = 0; czero = 0; }
    __syncthreads();
    const unsigned int* xw = (const unsigned int*)x;
    unsigned int w = xw[t * 4];
    int e_lo = (int)((w >> 7) & 0xFF);
    if (e_lo >= 100 && e_lo <= 140) atomicAdd(&cbf, 1);
    const unsigned int* ew = (const unsigned int*)ei;
    if (ew[2 * t + 1] == 0u) atomicAdd(&czero, 1);
    __syncthreads();
    if (t == 0) {
        int isb = (cbf >= 192) ? 1 : 0;
        flags[0] = isb;
        flags[1] = (czero >= 250) ? 1 : 0;
        isbS = isb;
    }
    __syncthreads();
    int isb = isbS;
    for (int j = 0; j < pk.n; ++j) {
        const void* s = pk.src[j];
        int c = pk.cnt[j], o = pk.dstoff[j];
        for (int i = t; i < c; i += blockDim.x) {
            float v = isb ? b2f(((const bf16*)s)[i]) : ((const float*)s)[i];
            dst[o + i] = v;
        }
    }
}

static __device__ __forceinline__ int ld_src(const int* ei, int E, int e, int i64) {
    return i64 ? ei[2ll * e] : ei[e];
}
static __device__ __forceinline__ int ld_dst(const int* ei, int E, int e, int i64) {
    return i64 ? ei[2ll * (E + e)] : ei[(long long)E + e];
}

// ---------------- CSR build: two-level bucket counting sort, key=(dstLow<<3)|srcSlice ----------

__global__ void bucket_count(const int* __restrict__ ei, int E, const int* __restrict__ flags,
                             int* __restrict__ bcnt, int NB) {
    __shared__ int lh[NBMAX];
    int tid = threadIdx.x;
    for (int i = tid; i < NB; i += 256) lh[i] = 0;
    __syncthreads();
    int i64 = flags[1];
    int stride = gridDim.x * 256;
    for (int e = blockIdx.x * 256 + tid; e < E; e += stride)
        atomicAdd(&lh[ld_dst(ei, E, e, i64) >> BSH], 1);
    __syncthreads();
    for (int i = tid; i < NB; i += 256)
        if (lh[i]) atomicAdd(&bcnt[i], lh[i]);
}

__global__ void scan_buckets(const int* __restrict__ bcnt, int NB, int E,
                             int* __restrict__ gBase, int* __restrict__ gCursor,
                             int* __restrict__ rowStart, int N) {
    __shared__ int part[256];
    int t = threadIdx.x;
    int per = (NB + 255) >> 8;
    int lo = t * per, hi = min(lo + per, NB);
    int s = 0;
    for (int i = lo; i < hi; ++i) s += bcnt[i];
    part[t] = s;
    __syncthreads();
    for (int off = 1; off < 256; off <<= 1) {
        int v = (t >= off) ? part[t - off] : 0;
        __syncthreads();
        part[t] += v;
        __syncthreads();
    }
    int acc = (t == 0) ? 0 : part[t - 1];
    for (int i = lo; i < hi; ++i) {
        gBase[i] = acc; gCursor[i] = acc;
        acc += bcnt[i];
    }
    if (t == 0) { gBase[NB] = E; rowStart[N] = E; }
}

__global__ void bucket_scatter(const int* __restrict__ ei, int E, const int* __restrict__ flags,
                               int* __restrict__ gCursor, uint2* __restrict__ binned, int NB) {
    __shared__ int lh[NBMAX];
    __shared__ int lbase[NBMAX];
    __shared__ int lcur[NBMAX];
    int tid = threadIdx.x;
    int i64 = flags[1];
    int nchunk = (E + CHK - 1) / CHK;
    for (int chunk = blockIdx.x; chunk < nchunk; chunk += gridDim.x) {
        int c0 = chunk * CHK;
        int c1 = min(c0 + CHK, E);
        for (int i = tid; i < NB; i += 256) lh[i] = 0;
        __syncthreads();
        for (int e = c0 + tid; e < c1; e += 256)
            atomicAdd(&lh[ld_dst(ei, E, e, i64) >> BSH], 1);
        __syncthreads();
        for (int b = tid; b < NB; b += 256) {
            int c = lh[b];
            lbase[b] = c ? atomicAdd(&gCursor[b], c) : 0;
            lcur[b] = 0;
        }
        __syncthreads();
        for (int e = c0 + tid; e < c1; e += 256) {
            int d = ld_dst(ei, E, e, i64);
            int s = ld_src(ei, E, e, i64);
            int b = d >> BSH;
            int off = atomicAdd(&lcur[b], 1);
            unsigned key = ((unsigned)(d & (BS - 1)) << 3) | (unsigned)min(s >> 16, 7);
            binned[lbase[b] + off] = make_uint2((unsigned)s, key);
        }
        __syncthreads();
    }
}

// per-bucket counting sort on 13-bit key -> csrSrc (rows slice-ordered) + rowStart
__global__ void bucket_sort(const uint2* __restrict__ binned, const int* __restrict__ gBase,
                            int* __restrict__ csrSrc, int* __restrict__ rowStart, int N) {
    __shared__ int hist[KEYS];
    __shared__ int tsum[1024];
    int tid = threadIdx.x;
    int b = blockIdx.x;
    int base = gBase[b];
    int cnt = gBase[b + 1] - base;
    for (int i = tid; i < KEYS; i += 1024) hist[i] = 0;
    __syncthreads();
    for (int i = tid; i < cnt; i += 1024)
        atomicAdd(&hist[binned[base + i].y], 1);
    __syncthreads();
    // each thread owns 8 consecutive keys [8*tid, 8*tid+8) == all slices of dst (b*BS + tid)
    int c[8]; int s = 0;
#pragma unroll
    for (int k = 0; k < 8; ++k) { c[k] = hist[8 * tid + k]; s += c[k]; }
    tsum[tid] = s;
    __syncthreads();
    for (int off = 1; off < 1024; off <<= 1) {
        int v = (tid >= off) ? tsum[tid - off] : 0;
        __syncthreads();
        tsum[tid] += v;
        __syncthreads();
    }
    int excl = (tid == 0) ? 0 : tsum[tid - 1];
    int d = b * BS + tid;
    if (d < N) rowStart[d] = base + excl;
    int run = excl;
#pragma unroll
    for (int k = 0; k < 8; ++k) { hist[8 * tid + k] = run; run += c[k]; }
    __syncthreads();
    for (int i = tid; i < cnt; i += 1024) {
        uint2 pr = binned[base + i];
        int off = atomicAdd(&hist[pr.y], 1);
        csrSrc[base + off] = (int)pr.x;
    }
}

__global__ void graph_cnt_k(const int* __restrict__ batch, int N, float* __restrict__ gcnt) {
    int g = blockIdx.x * blockDim.x + threadIdx.x;
    if (g < NGRAPH) {
        int lo = 0, hi = N;
        while (lo < hi) { int mid = (lo + hi) >> 1; if (batch[mid] < g) lo = mid + 1; else hi = mid; }
        int lb = lo;
        lo = 0; hi = N;
        while (lo < hi) { int mid = (lo + hi) >> 1; if (batch[mid] <= g) lo = mid + 1; else hi = mid; }
        gcnt[g] = (float)(lo - lb);
    }
}

// ---------------- layer-0 node transform (writes bf16-packed h) ----------------
__global__ void node_feat0(const void* __restrict__ xin, int din,
                           const int* __restrict__ flags, const float* __restrict__ prmL,
                           unsigned int* __restrict__ hb, float* __restrict__ as_,
                           float* __restrict__ ad_, int N) {
    __shared__ float sW[256], sa[HID], sd[HID];
    int t = threadIdx.x;
    if (t < din * HID) sW[t] = prmL[t];
    if (t < HID) { sa[t] = prmL[256 + t]; sd[t] = prmL[272 + t]; }
    __syncthreads();
    int i = blockIdx.x * blockDim.x + t;
    if (i >= N) return;
    int isb = flags[0];
    const float* xf = (const float*)xin;
    const bf16* xb16 = (const bf16*)xin;
    float hr[HID];
#pragma unroll
    for (int j = 0; j < HID; ++j) hr[j] = 0.f;
    int base = i * din;
    for (int k = 0; k < din; ++k) {
        float xv = isb ? b2f(xb16[base + k]) : xf[base + k];
#pragma unroll
        for (int j = 0; j < HID; ++j) hr[j] = fmaf(xv, sW[k * HID + j], hr[j]);
    }
    float a1 = 0.f, a2 = 0.f;
#pragma unroll
    for (int j = 0; j < HID; ++j) { a1 = fmaf(hr[j], sa[j], a1); a2 = fmaf(hr[j], sd[j], a2); }
    uint4* hp = (uint4*)(hb + (i << 3));
    uint4 w0, w1;
    w0.x = pack2(hr[0], hr[1]);   w0.y = pack2(hr[2], hr[3]);
    w0.z = pack2(hr[4], hr[5]);   w0.w = pack2(hr[6], hr[7]);
    w1.x = pack2(hr[8], hr[9]);   w1.y = pack2(hr[10], hr[11]);
    w1.z = pack2(hr[12], hr[13]); w1.w = pack2(hr[14], hr[15]);
    hp[0] = w0; hp[1] = w1;
    as_[i] = a1; ad_[i] = a2;
}

// ---------------- GAT aggregation: slice-phased (8 phases, block barrier per phase) ----------
// rows are slice-sorted; phase s gathers only from hb slice s (2MB -> per-XCD L2-resident).
// whole grid (<=2048 blocks) co-resident at 8 blocks/CU so phases stay globally clustered.
__global__ void __launch_bounds__(256, 8)
gat_agg(const int* __restrict__ rowStart, const int* __restrict__ csrSrc,
        const unsigned int* __restrict__ hb, const float* __restrict__ as_,
        const float* __restrict__ ad_, const float* __restrict__ prmL,
        const int* __restrict__ batch,
        unsigned int* __restrict__ tb, float* __restrict__ gsum,
        float* __restrict__ gsumsq, int N) {
    __shared__ float sv[256][HID + 1];
    __shared__ int sg[256];
    int tid = threadIdx.x;
    int node = blockIdx.x * 256 + tid;
    bool valid = node < N;
    int start = 0, end = 0;
    float adi = 0.f, e_self = 0.f;
    if (valid) {
        start = rowStart[node];
        end = rowStart[node + 1];
        adi = ad_[node];
        float zs = as_[node] + adi;
        e_self = zs > 0.f ? zs : NEG_SLOPE * zs;
    }
    float acc[HID];
#pragma unroll
    for (int f = 0; f < HID; ++f) acc[f] = 0.f;
    float m = e_self, ssum = 0.f;
    int p = start;
    for (int s = 0; s < NSLICE; ++s) {
        while (p < end) {
            int rem = end - p;
            int i0 = csrSrc[p];
            int i1 = (rem > 1) ? csrSrc[p + 1] : i0;
            int i2 = (rem > 2) ? csrSrc[p + 2] : i0;
            int i3 = (rem > 3) ? csrSrc[p + 3] : i0;
            bool m0 = min(i0 >> 16, 7) == s;
            bool m1 = (rem > 1) && (min(i1 >> 16, 7) == s);
            bool m2 = (rem > 2) && (min(i2 >> 16, 7) == s);
            bool m3 = (rem > 3) && (min(i3 >> 16, 7) == s);
            int k = m0 ? (m1 ? (m2 ? (m3 ? 4 : 3) : 2) : 1) : 0;
            if (k == 0) break;
            int s1 = m1 ? i1 : i0;
            int s2 = m2 ? i2 : i0;
            int s3 = m3 ? i3 : i0;
            float a0 = as_[i0], a1 = as_[s1], a2 = as_[s2], a3 = as_[s3];
            const uint4* h0 = (const uint4*)(hb + (i0 << 3));
            const uint4* h1 = (const uint4*)(hb + (s1 << 3));
            const uint4* h2 = (const uint4*)(hb + (s2 << 3));
            const uint4* h3 = (const uint4*)(hb + (s3 << 3));
            uint4 r00 = h0[0], r01 = h0[1];
            uint4 r10 = h1[0], r11 = h1[1];
            uint4 r20 = h2[0], r21 = h2[1];
            uint4 r30 = h3[0], r31 = h3[1];
            float z0 = a0 + adi, z1 = a1 + adi, z2 = a2 + adi, z3 = a3 + adi;
            float e0 = z0 > 0.f ? z0 : NEG_SLOPE * z0;
            float e1 = m1 ? (z1 > 0.f ? z1 : NEG_SLOPE * z1) : -1e30f;
            float e2 = m2 ? (z2 > 0.f ? z2 : NEG_SLOPE * z2) : -1e30f;
            float e3 = m3 ? (z3 > 0.f ? z3 : NEG_SLOPE * z3) : -1e30f;
            float cm = fmaxf(fmaxf(e0, e1), fmaxf(e2, e3));
            if (cm > m) {
                float sc = __expf(m - cm);
                ssum *= sc;
#pragma unroll
                for (int f = 0; f < HID; ++f) acc[f] *= sc;
                m = cm;
            }
            float p0 = __expf(e0 - m);
            float p1 = __expf(e1 - m);
            float p2 = __expf(e2 - m);
            float p3 = __expf(e3 - m);
            ssum += p0 + p1 + p2 + p3;
            fma_row(r00, r01, p0, acc);
            fma_row(r10, r11, p1, acc);
            fma_row(r20, r21, p2, acc);
            fma_row(r30, r31, p3, acc);
            p += k;
            if (k < 4) break;
        }
        __syncthreads();   // phase barrier (uniform: all lanes run 8 phases)
    }
    float tv[HID];
    int g = -1;
    if (valid) {
        const uint4* hs = (const uint4*)(hb + (node << 3));
        uint4 rs0 = hs[0], rs1 = hs[1];
        float pself = __expf(e_self - m);
        ssum += pself;
        fma_row(rs0, rs1, pself, acc);
        float inv = 1.f / ssum;
#pragma unroll
        for (int f = 0; f < HID; ++f) tv[f] = fmaf(acc[f], inv, prmL[288 + f]);
        uint4* tp = (uint4*)(tb + (node << 3));
        uint4 w0, w1;
        w0.x = pack2(tv[0], tv[1]);   w0.y = pack2(tv[2], tv[3]);
        w0.z = pack2(tv[4], tv[5]);   w0.w = pack2(tv[6], tv[7]);
        w1.x = pack2(tv[8], tv[9]);   w1.y = pack2(tv[10], tv[11]);
        w1.z = pack2(tv[12], tv[13]); w1.w = pack2(tv[14], tv[15]);
        tp[0] = w0; tp[1] = w1;
        g = batch[node];
    }
    sg[tid] = valid ? g : -1;
#pragma unroll
    for (int f = 0; f < HID; ++f) sv[tid][f] = valid ? tv[f] : 0.f;
    __syncthreads();
    if (tid < 64) {
        int f = tid & 15;
        int seg = tid >> 4;
        int n0 = seg * 64, n1 = n0 + 64;
        float s1 = 0.f, s2 = 0.f;
        int cur = -2;
        for (int n = n0; n < n1; ++n) {
            int bg = sg[n];
            if (bg < 0) continue;
            if (bg != cur) {
                if (cur >= 0) { atomicAdd(&gsum[cur * HID + f], s1); atomicAdd(&gsumsq[cur * HID + f], s2); }
                cur = bg; s1 = 0.f; s2 = 0.f;
            }
            float v = sv[n][f];
            s1 += v; s2 += v * v;
        }
        if (cur >= 0) { atomicAdd(&gsum[cur * HID + f], s1); atomicAdd(&gsumsq[cur * HID + f], s2); }
    }
}

// ---------------- fused GraphNorm (inline coeffs) + relu(+residual) + next features / pool ----
__global__ void norm_feat(const unsigned int* __restrict__ tb,
                          const float* __restrict__ gsum, const float* __restrict__ gsumsq,
                          const float* __restrict__ gcnt, const int* __restrict__ batch,
                          unsigned int* __restrict__ xb, int N, int residual, int isLast,
                          const float* __restrict__ prmL, const float* __restrict__ prmNext,
                          unsigned int* __restrict__ hb, float* __restrict__ as_,
                          float* __restrict__ ad_, float* __restrict__ pooled) {
    __shared__ float sW[256], sa[HID], sd[HID];
    __shared__ float sgw[HID], sgb[HID], sga[HID];
    __shared__ float sv[256][HID + 1];
    __shared__ int sg[256];
    int tid = threadIdx.x;
    if (!isLast) {
        sW[tid] = prmNext[tid];
        if (tid < HID) { sa[tid] = prmNext[256 + tid]; sd[tid] = prmNext[272 + tid]; }
    }
    if (tid < HID) { sgw[tid] = prmL[304 + tid]; sgb[tid] = prmL[320 + tid]; sga[tid] = prmL[336 + tid]; }
    __syncthreads();
    int i = blockIdx.x * 256 + tid;
    float v[HID];
    int g = -1;
    if (i < N) {
        g = batch[i];
        float invc = 1.f / gcnt[g];
        const uint4* tp = (const uint4*)(tb + (i << 3));
        uint4 u0 = tp[0], u1 = tp[1];
        unsigned int us[8] = {u0.x, u0.y, u0.z, u0.w, u1.x, u1.y, u1.z, u1.w};
        float ts[HID];
#pragma unroll
        for (int q = 0; q < 8; ++q) {
            ts[2 * q]     = __uint_as_float(us[q] << 16);
            ts[2 * q + 1] = __uint_as_float(us[q] & 0xFFFF0000u);
        }
        float xs[HID];
        if (residual) {
            const uint4* xp = (const uint4*)(xb + (i << 3));
            uint4 y0 = xp[0], y1 = xp[1];
            unsigned int uy[8] = {y0.x, y0.y, y0.z, y0.w, y1.x, y1.y, y1.z, y1.w};
#pragma unroll
            for (int q = 0; q < 8; ++q) {
                xs[2 * q]     = __uint_as_float(uy[q] << 16);
                xs[2 * q + 1] = __uint_as_float(uy[q] & 0xFFFF0000u);
            }
        } else {
#pragma unroll
            for (int f = 0; f < HID; ++f) xs[f] = 0.f;
        }
        const float4* s1p = (const float4*)(gsum + g * HID);
        const float4* s2p = (const float4*)(gsumsq + g * HID);
        float4 sa4[4], sb4[4];
#pragma unroll
        for (int q = 0; q < 4; ++q) { sa4[q] = s1p[q]; sb4[q] = s2p[q]; }
        float s1v[HID], s2v[HID];
#pragma unroll
        for (int q = 0; q < 4; ++q) {
            s1v[q*4+0] = sa4[q].x; s1v[q*4+1] = sa4[q].y; s1v[q*4+2] = sa4[q].z; s1v[q*4+3] = sa4[q].w;
            s2v[q*4+0] = sb4[q].x; s2v[q*4+1] = sb4[q].y; s2v[q*4+2] = sb4[q].z; s2v[q*4+3] = sb4[q].w;
        }
#pragma unroll
        for (int f = 0; f < HID; ++f) {
            float mean = s1v[f] * invc;
            float msq = s2v[f] * invc;
            float ga = sga[f];
            float var = msq + (ga * ga - 2.f * ga) * mean * mean;
            var = fmaxf(var, 0.f);
            float A = sgw[f] * rsqrtf(var + EPS_GN);
            float B = sgb[f] - A * ga * mean;
            float val = fmaf(A, ts[f], B) + xs[f];
            v[f] = fmaxf(val, 0.f);
        }
    }
    if (isLast) {
        sg[tid] = (i < N) ? g : -1;
#pragma unroll
        for (int f = 0; f < HID; ++f) sv[tid][f] = (i < N) ? v[f] : 0.f;
        __syncthreads();
        if (tid < 64) {
            int f = tid & 15;
            int seg = tid >> 4;
            int n0 = seg * 64, n1 = n0 + 64;
            float s1 = 0.f;
            int cur = -2;
            for (int n = n0; n < n1; ++n) {
                int bg = sg[n];
                if (bg < 0) continue;
                if (bg != cur) { if (cur >= 0) atomicAdd(&pooled[cur * HID + f], s1); cur = bg; s1 = 0.f; }
                s1 += sv[n][f];
            }
            if (cur >= 0) atomicAdd(&pooled[cur * HID + f], s1);
        }
    } else if (i < N) {
        uint4* xp = (uint4*)(xb + (i << 3));
        uint4 y0, y1;
        y0.x = pack2(v[0], v[1]);   y0.y = pack2(v[2], v[3]);
        y0.z = pack2(v[4], v[5]);   y0.w = pack2(v[6], v[7]);
        y1.x = pack2(v[8], v[9]);   y1.y = pack2(v[10], v[11]);
        y1.z = pack2(v[12], v[13]); y1.w = pack2(v[14], v[15]);
        xp[0] = y0; xp[1] = y1;
        float hr[HID];
#pragma unroll
        for (int j = 0; j < HID; ++j) hr[j] = 0.f;
#pragma unroll
        for (int k = 0; k < HID; ++k) {
            float xv = v[k];
#pragma unroll
            for (int j = 0; j < HID; ++j) hr[j] = fmaf(xv, sW[k * HID + j], hr[j]);
        }
        float a1 = 0.f, a2 = 0.f;
#pragma unroll
        for (int j = 0; j < HID; ++j) { a1 = fmaf(hr[j], sa[j], a1); a2 = fmaf(hr[j], sd[j], a2); }
        uint4* hp = (uint4*)(hb + (i << 3));
        uint4 w0, w1;
        w0.x = pack2(hr[0], hr[1]);   w0.y = pack2(hr[2], hr[3]);
        w0.z = pack2(hr[4], hr[5]);   w0.w = pack2(hr[6], hr[7]);
        w1.x = pack2(hr[8], hr[9]);   w1.y = pack2(hr[10], hr[11]);
        w1.z = pack2(hr[12], hr[13]); w1.w = pack2(hr[14], hr[15]);
        hp[0] = w0; hp[1] = w1;
        as_[i] = a1; ad_[i] = a2;
    }
}

// ---------------- final linear ----------------
__global__ void final_lin(const float* __restrict__ pooled, const float* __restrict__ gcnt,
                          const float* __restrict__ prm, const int* __restrict__ flags,
                          void* __restrict__ out) {
    int g = blockIdx.x * blockDim.x + threadIdx.x;
    if (g < NGRAPH) {
        float c = gcnt[g];
        float invc = c > 0.f ? 1.f / c : 0.f;
        float o0 = prm[1440], o1 = prm[1441];
#pragma unroll
        for (int f = 0; f < HID; ++f) {
            float p = pooled[g * HID + f] * invc;
            o0 = fmaf(p, prm[1408 + f * 2 + 0], o0);
            o1 = fmaf(p, prm[1408 + f * 2 + 1], o1);
        }
        if (flags[0]) {
            ((bf16*)out)[g * 2 + 0] = __float2bfloat16(o0);
            ((bf16*)out)[g * 2 + 1] = __float2bfloat16(o1);
        } else {
            ((float*)out)[g * 2 + 0] = o0;
            ((float*)out)[g * 2 + 1] = o1;
        }
    }
}

extern "C" void kernel_launch(void* const* d_in, const int* in_sizes, int n_in,
                              void* d_out, int out_size, void* d_ws, size_t ws_size,
                              hipStream_t stream) {
    const void* x = d_in[0];
    const int* ei = (const int*)d_in[1];
    const int* batch = (const int*)d_in[2];
    int N = in_sizes[2];
    int E = in_sizes[1] / 2;
    int din0 = in_sizes[0] / N;
    int NB = (N + BS - 1) / BS;

    float* ws = (float*)d_ws;
    int* flags = (int*)ws;                          // 16 ints
    float* prm = ws + 16;                           // 2048 floats
    unsigned int* hb = (unsigned int*)(ws + 4096);  // N*8 u32 (bf16 h)
    unsigned int* tb = hb + (size_t)N * 8;          // N*8 u32 (bf16 t)
    unsigned int* xb = tb + (size_t)N * 8;          // N*8 u32 (bf16 xcur)
    float* as_ = (float*)(xb + (size_t)N * 8);      // N
    float* ad_ = as_ + N;                           // N
    int* rowStart = (int*)(ad_ + N);                // N+1
    int* gBase = rowStart + (N + 1);                // NBMAX+1
    int* gCursor = gBase + NBMAX + 1;               // NBMAX
    int* csrSrc = gCursor + NBMAX;                  // E (+pad)
    int* bcnt = csrSrc + E + 64;                    // NBMAX   -- start of single-memset region
    float* gstat = (float*)(bcnt + NBMAX);          // 4 layers * 2 * G*HID = 128000
    float* pooled = gstat + 4 * 2 * NGRAPH * HID;   // G*HID
    float* gcnt = pooled + NGRAPH * HID;            // G (written by graph_cnt_k, no memset)
    uint2* binned = (uint2*)hb;   // E*8B <= 48MB (hb+tb+xb); all dead until after bucket_sort

    PtrPack pk;
    int n = 0;
    for (int l = 0; l < 4; ++l) {
        int dl = (l == 0) ? din0 : HID;
        int base = l * 352;
        const int offs[7] = {0, 256, 272, 288, 304, 320, 336};
        const int cnts[7] = {dl * HID, HID, HID, HID, HID, HID, HID};
        for (int j = 0; j < 7; ++j) {
            pk.src[n] = d_in[4 + l * 7 + j];
            pk.cnt[n] = cnts[j];
            pk.dstoff[n] = base + offs[j];
            ++n;
        }
    }
    pk.src[n] = d_in[32]; pk.cnt[n] = HID * 2; pk.dstoff[n] = 1408; ++n;
    pk.src[n] = d_in[33]; pk.cnt[n] = 2;       pk.dstoff[n] = 1440; ++n;
    pk.n = n;

    int nbN = (N + 255) / 256;

    detect_cvt<<<1, 256, 0, stream>>>(x, ei, flags, pk, prm);

    // one memset covers bcnt + all per-layer stats + pooled
    size_t zbytes = (size_t)(NBMAX + 4 * 2 * NGRAPH * HID + NGRAPH * HID) * sizeof(int);
    hipMemsetAsync(bcnt, 0, zbytes, stream);

    bucket_count<<<1024, 256, 0, stream>>>(ei, E, flags, bcnt, NB);
    scan_buckets<<<1, 256, 0, stream>>>(bcnt, NB, E, gBase, gCursor, rowStart, N);
    bucket_scatter<<<1024, 256, 0, stream>>>(ei, E, flags, gCursor, binned, NB);
    bucket_sort<<<NB, 1024, 0, stream>>>(binned, gBase, csrSrc, rowStart, N);
    graph_cnt_k<<<(NGRAPH + 255) / 256, 256, 0, stream>>>(batch, N, gcnt);

    node_feat0<<<nbN, 256, 0, stream>>>(x, din0, flags, prm, hb, as_, ad_, N);

    for (int l = 0; l < 4; ++l) {
        const float* prmL = prm + l * 352;
        const float* prmNext = prm + (l + 1 < 4 ? (l + 1) * 352 : 0);
        float* gsumL = gstat + l * 2 * NGRAPH * HID;
        float* gsumsqL = gsumL + NGRAPH * HID;

        gat_agg<<<nbN, 256, 0, stream>>>(rowStart, csrSrc, hb, as_, ad_, prmL, batch,
                                         tb, gsumL, gsumsqL, N);
        norm_feat<<<nbN, 256, 0, stream>>>(tb, gsumL, gsumsqL, gcnt, batch, xb, N,
                                           l > 0 ? 1 : 0, l == 3 ? 1 : 0, prmL, prmNext,
                                           hb, as_, ad_, pooled);
    }

    final_lin<<<(NGRAPH + 255) / 256, 256, 0, stream>>>(pooled, gcnt, prm, flags, d_out);
}

// Round 10
// 1004.741 us; speedup vs baseline: 3.4643x; 3.4643x over previous
//
#include <hip/hip_runtime.h>
#include <hip/hip_bf16.h>

#define HID 16
#define NGRAPH 1000
#define NEG_SLOPE 0.2f
#define EPS_GN 1e-5f
#define BSH 10              // bucket shift: 1024 dsts per bucket
#define BS 1024             // bucket span (power of 2)
#define KEYS 8192           // BS * 8 slices
#define NBMAX 2048
#define CHK 4096            // edges per scatter chunk

typedef __hip_bfloat16 bf16;

static __device__ __forceinline__ float b2f(bf16 v) { return __bfloat162float(v); }

// pack two floats into one u32 holding two RNE-rounded bf16s (a=low, b=high)
static __device__ __forceinline__ unsigned int pack2(float a, float b) {
    unsigned int ia = __float_as_uint(a);
    unsigned int ib = __float_as_uint(b);
    ia += 0x7FFFu + ((ia >> 16) & 1u);
    ib += 0x7FFFu + ((ib >> 16) & 1u);
    return (ia >> 16) | (ib & 0xFFFF0000u);
}

// acc[0..15] += p * bf16row(ra,rb)
static __device__ __forceinline__ void fma_row(const uint4 ra, const uint4 rb, float p,
                                               float* __restrict__ acc) {
    unsigned int us[8] = {ra.x, ra.y, ra.z, ra.w, rb.x, rb.y, rb.z, rb.w};
#pragma unroll
    for (int q = 0; q < 8; ++q) {
        float lo = __uint_as_float(us[q] << 16);
        float hi = __uint_as_float(us[q] & 0xFFFF0000u);
        acc[2 * q]     = fmaf(p, lo, acc[2 * q]);
        acc[2 * q + 1] = fmaf(p, hi, acc[2 * q + 1]);
    }
}

struct PtrPack { const void* src[30]; int cnt[30]; int dstoff[30]; int n; };

// ---------------- dtype detection + param conversion (single block) ----------------
__global__ void detect_cvt(const void* x, const void* ei, int* flags, PtrPack pk,
                           float* __restrict__ dst) {
    __shared__ int cbf, czero;
    __shared__ int isbS;
    int t = threadIdx.x;
    if (t == 0) { cbf = 0; czero = 0; }
    __syncthreads();
    const unsigned int* xw = (const unsigned int*)x;
    unsigned int w = xw[t * 4];
    int e_lo = (int)((w >> 7) & 0xFF);
    if (e_lo >= 100 && e_lo <= 140) atomicAdd(&cbf, 1);
    const unsigned int* ew = (const unsigned int*)ei;
    if (ew[2 * t + 1] == 0u) atomicAdd(&czero, 1);
    __syncthreads();
    if (t == 0) {
        int isb = (cbf >= 192) ? 1 : 0;
        flags[0] = isb;
        flags[1] = (czero >= 250) ? 1 : 0;
        isbS = isb;
    }
    __syncthreads();
    int isb = isbS;
    for (int j = 0; j < pk.n; ++j) {
        const void* s = pk.src[j];
        int c = pk.cnt[j], o = pk.dstoff[j];
        for (int i = t; i < c; i += blockDim.x) {
            float v = isb ? b2f(((const bf16*)s)[i]) : ((const float*)s)[i];
            dst[o + i] = v;
        }
    }
}

static __device__ __forceinline__ int ld_src(const int* ei, int E, int e, int i64) {
    return i64 ? ei[2ll * e] : ei[e];
}
static __device__ __forceinline__ int ld_dst(const int* ei, int E, int e, int i64) {
    return i64 ? ei[2ll * (E + e)] : ei[(long long)E + e];
}

// ---------------- CSR build: two-level bucket counting sort ----------------

__global__ void bucket_count(const int* __restrict__ ei, int E, const int* __restrict__ flags,
                             int* __restrict__ bcnt, int NB) {
    __shared__ int lh[NBMAX];
    int tid = threadIdx.x;
    for (int i = tid; i < NB; i += 256) lh[i] = 0;
    __syncthreads();
    int i64 = flags[1];
    int stride = gridDim.x * 256;
    for (int e = blockIdx.x * 256 + tid; e < E; e += stride)
        atomicAdd(&lh[ld_dst(ei, E, e, i64) >> BSH], 1);
    __syncthreads();
    for (int i = tid; i < NB; i += 256)
        if (lh[i]) atomicAdd(&bcnt[i], lh[i]);
}

__global__ void scan_buckets(const int* __restrict__ bcnt, int NB, int E,
                             int* __restrict__ gBase, int* __restrict__ gCursor,
                             int* __restrict__ rowStart, int N) {
    __shared__ int part[256];
    int t = threadIdx.x;
    int per = (NB + 255) >> 8;
    int lo = t * per, hi = min(lo + per, NB);
    int s = 0;
    for (int i = lo; i < hi; ++i) s += bcnt[i];
    part[t] = s;
    __syncthreads();
    for (int off = 1; off < 256; off <<= 1) {
        int v = (t >= off) ? part[t - off] : 0;
        __syncthreads();
        part[t] += v;
        __syncthreads();
    }
    int acc = (t == 0) ? 0 : part[t - 1];
    for (int i = lo; i < hi; ++i) {
        gBase[i] = acc; gCursor[i] = acc;
        acc += bcnt[i];
    }
    if (t == 0) { gBase[NB] = E; rowStart[N] = E; }
}

__global__ void bucket_scatter(const int* __restrict__ ei, int E, const int* __restrict__ flags,
                               int* __restrict__ gCursor, uint2* __restrict__ binned, int NB) {
    __shared__ int lh[NBMAX];
    __shared__ int lbase[NBMAX];
    __shared__ int lcur[NBMAX];
    int tid = threadIdx.x;
    int i64 = flags[1];
    int nchunk = (E + CHK - 1) / CHK;
    for (int chunk = blockIdx.x; chunk < nchunk; chunk += gridDim.x) {
        int c0 = chunk * CHK;
        int c1 = min(c0 + CHK, E);
        for (int i = tid; i < NB; i += 256) lh[i] = 0;
        __syncthreads();
        for (int e = c0 + tid; e < c1; e += 256)
            atomicAdd(&lh[ld_dst(ei, E, e, i64) >> BSH], 1);
        __syncthreads();
        for (int b = tid; b < NB; b += 256) {
            int c = lh[b];
            lbase[b] = c ? atomicAdd(&gCursor[b], c) : 0;
            lcur[b] = 0;
        }
        __syncthreads();
        for (int e = c0 + tid; e < c1; e += 256) {
            int d = ld_dst(ei, E, e, i64);
            int s = ld_src(ei, E, e, i64);
            int b = d >> BSH;
            int off = atomicAdd(&lcur[b], 1);
            unsigned key = ((unsigned)(d & (BS - 1)) << 3) | (unsigned)min(s >> 16, 7);
            binned[lbase[b] + off] = make_uint2((unsigned)s, key);
        }
        __syncthreads();
    }
}

// per-bucket counting sort on 13-bit key -> csrSrc + rowStart
__global__ void bucket_sort(const uint2* __restrict__ binned, const int* __restrict__ gBase,
                            int* __restrict__ csrSrc, int* __restrict__ rowStart, int N) {
    __shared__ int hist[KEYS];
    __shared__ int tsum[1024];
    int tid = threadIdx.x;
    int b = blockIdx.x;
    int base = gBase[b];
    int cnt = gBase[b + 1] - base;
    for (int i = tid; i < KEYS; i += 1024) hist[i] = 0;
    __syncthreads();
    for (int i = tid; i < cnt; i += 1024)
        atomicAdd(&hist[binned[base + i].y], 1);
    __syncthreads();
    int c[8]; int s = 0;
#pragma unroll
    for (int k = 0; k < 8; ++k) { c[k] = hist[8 * tid + k]; s += c[k]; }
    tsum[tid] = s;
    __syncthreads();
    for (int off = 1; off < 1024; off <<= 1) {
        int v = (tid >= off) ? tsum[tid - off] : 0;
        __syncthreads();
        tsum[tid] += v;
        __syncthreads();
    }
    int excl = (tid == 0) ? 0 : tsum[tid - 1];
    int d = b * BS + tid;
    if (d < N) rowStart[d] = base + excl;
    int run = excl;
#pragma unroll
    for (int k = 0; k < 8; ++k) { hist[8 * tid + k] = run; run += c[k]; }
    __syncthreads();
    for (int i = tid; i < cnt; i += 1024) {
        uint2 pr = binned[base + i];
        int off = atomicAdd(&hist[pr.y], 1);
        csrSrc[base + off] = (int)pr.x;
    }
}

__global__ void graph_cnt_k(const int* __restrict__ batch, int N, float* __restrict__ gcnt) {
    int g = blockIdx.x * blockDim.x + threadIdx.x;
    if (g < NGRAPH) {
        int lo = 0, hi = N;
        while (lo < hi) { int mid = (lo + hi) >> 1; if (batch[mid] < g) lo = mid + 1; else hi = mid; }
        int lb = lo;
        lo = 0; hi = N;
        while (lo < hi) { int mid = (lo + hi) >> 1; if (batch[mid] <= g) lo = mid + 1; else hi = mid; }
        gcnt[g] = (float)(lo - lb);
    }
}

// ---------------- layer-0 node transform (writes bf16-packed h) ----------------
__global__ void node_feat0(const void* __restrict__ xin, int din,
                           const int* __restrict__ flags, const float* __restrict__ prmL,
                           unsigned int* __restrict__ hb, float* __restrict__ as_,
                           float* __restrict__ ad_, int N) {
    __shared__ float sW[256], sa[HID], sd[HID];
    int t = threadIdx.x;
    if (t < din * HID) sW[t] = prmL[t];
    if (t < HID) { sa[t] = prmL[256 + t]; sd[t] = prmL[272 + t]; }
    __syncthreads();
    int i = blockIdx.x * blockDim.x + t;
    if (i >= N) return;
    int isb = flags[0];
    const float* xf = (const float*)xin;
    const bf16* xb16 = (const bf16*)xin;
    float hr[HID];
#pragma unroll
    for (int j = 0; j < HID; ++j) hr[j] = 0.f;
    int base = i * din;
    for (int k = 0; k < din; ++k) {
        float xv = isb ? b2f(xb16[base + k]) : xf[base + k];
#pragma unroll
        for (int j = 0; j < HID; ++j) hr[j] = fmaf(xv, sW[k * HID + j], hr[j]);
    }
    float a1 = 0.f, a2 = 0.f;
#pragma unroll
    for (int j = 0; j < HID; ++j) { a1 = fmaf(hr[j], sa[j], a1); a2 = fmaf(hr[j], sd[j], a2); }
    uint4* hp = (uint4*)(hb + (i << 3));
    uint4 w0, w1;
    w0.x = pack2(hr[0], hr[1]);   w0.y = pack2(hr[2], hr[3]);
    w0.z = pack2(hr[4], hr[5]);   w0.w = pack2(hr[6], hr[7]);
    w1.x = pack2(hr[8], hr[9]);   w1.y = pack2(hr[10], hr[11]);
    w1.z = pack2(hr[12], hr[13]); w1.w = pack2(hr[14], hr[15]);
    hp[0] = w0; hp[1] = w1;
    as_[i] = a1; ad_[i] = a2;
}

// ---------------- GAT aggregation: lane-per-node, chunk-4 + index prefetch, bf16 h/t ----------
// chunk-4 + launch_bounds(256,4): PROVEN sweet spot (r8: 48 VGPR, no spill, 133us).
// DO NOT raise occupancy bound (r9: (256,8) -> 64-VGPR cap -> acc[] spills -> 5.7x slower).
// DO NOT widen to chunk-8 (r7: >128 VGPR -> spill -> 1.7x slower).
__global__ void __launch_bounds__(256, 4)
gat_agg(const int* __restrict__ rowStart, const int* __restrict__ csrSrc,
        const unsigned int* __restrict__ hb, const float* __restrict__ as_,
        const float* __restrict__ ad_, const float* __restrict__ prmL,
        const int* __restrict__ batch,
        unsigned int* __restrict__ tb, float* __restrict__ gsum,
        float* __restrict__ gsumsq, int N) {
    __shared__ float sv[256][HID + 1];
    __shared__ int sg[256];
    int tid = threadIdx.x;
    int node = blockIdx.x * 256 + tid;
    bool valid = node < N;
    float acc[HID];
    float tv[HID];
    int g = -1;
    if (valid) {
        int start = rowStart[node];
        int end = rowStart[node + 1];
        float adi = ad_[node];
        float zs = as_[node] + adi;
        float e_self = zs > 0.f ? zs : NEG_SLOPE * zs;
        float m = e_self, ssum = 0.f;
#pragma unroll
        for (int f = 0; f < HID; ++f) acc[f] = 0.f;
        int s[4];
        if (start < end) {
            int rem = end - start;
            s[0] = csrSrc[start];
#pragma unroll
            for (int k = 1; k < 4; ++k) s[k] = (k < rem) ? csrSrc[start + k] : s[0];
        }
        for (int base = start; base < end; base += 4) {
            int rem = end - base;
            float a0 = as_[s[0]], a1 = as_[s[1]], a2 = as_[s[2]], a3 = as_[s[3]];
            const uint4* h0 = (const uint4*)(hb + (s[0] << 3));
            const uint4* h1 = (const uint4*)(hb + (s[1] << 3));
            const uint4* h2 = (const uint4*)(hb + (s[2] << 3));
            const uint4* h3 = (const uint4*)(hb + (s[3] << 3));
            uint4 r00 = h0[0], r01 = h0[1];
            uint4 r10 = h1[0], r11 = h1[1];
            uint4 r20 = h2[0], r21 = h2[1];
            uint4 r30 = h3[0], r31 = h3[1];
            int nbase = base + 4;
            if (nbase < end) {
                int nrem = end - nbase;
                int sn0 = csrSrc[nbase];
                s[0] = sn0;
#pragma unroll
                for (int k = 1; k < 4; ++k) s[k] = (k < nrem) ? csrSrc[nbase + k] : sn0;
            }
            float z0 = a0 + adi, z1 = a1 + adi, z2 = a2 + adi, z3 = a3 + adi;
            float e0 = z0 > 0.f ? z0 : NEG_SLOPE * z0;
            float e1 = (1 < rem) ? (z1 > 0.f ? z1 : NEG_SLOPE * z1) : -1e30f;
            float e2 = (2 < rem) ? (z2 > 0.f ? z2 : NEG_SLOPE * z2) : -1e30f;
            float e3 = (3 < rem) ? (z3 > 0.f ? z3 : NEG_SLOPE * z3) : -1e30f;
            float cm = fmaxf(fmaxf(e0, e1), fmaxf(e2, e3));
            if (cm > m) {
                float sc = __expf(m - cm);
                ssum *= sc;
#pragma unroll
                for (int f = 0; f < HID; ++f) acc[f] *= sc;
                m = cm;
            }
            float p0 = __expf(e0 - m);
            float p1 = __expf(e1 - m);
            float p2 = __expf(e2 - m);
            float p3 = __expf(e3 - m);
            ssum += p0 + p1 + p2 + p3;
            fma_row(r00, r01, p0, acc);
            fma_row(r10, r11, p1, acc);
            fma_row(r20, r21, p2, acc);
            fma_row(r30, r31, p3, acc);
        }
        const uint4* hs = (const uint4*)(hb + (node << 3));
        uint4 rs0 = hs[0], rs1 = hs[1];
        float pself = __expf(e_self - m);
        ssum += pself;
        fma_row(rs0, rs1, pself, acc);
        float inv = 1.f / ssum;
#pragma unroll
        for (int f = 0; f < HID; ++f) tv[f] = fmaf(acc[f], inv, prmL[288 + f]);
        uint4* tp = (uint4*)(tb + (node << 3));
        uint4 w0, w1;
        w0.x = pack2(tv[0], tv[1]);   w0.y = pack2(tv[2], tv[3]);
        w0.z = pack2(tv[4], tv[5]);   w0.w = pack2(tv[6], tv[7]);
        w1.x = pack2(tv[8], tv[9]);   w1.y = pack2(tv[10], tv[11]);
        w1.z = pack2(tv[12], tv[13]); w1.w = pack2(tv[14], tv[15]);
        tp[0] = w0; tp[1] = w1;
        g = batch[node];
    }
    sg[tid] = valid ? g : -1;
#pragma unroll
    for (int f = 0; f < HID; ++f) sv[tid][f] = valid ? tv[f] : 0.f;
    __syncthreads();
    if (tid < 64) {
        int f = tid & 15;
        int seg = tid >> 4;
        int n0 = seg * 64, n1 = n0 + 64;
        float s1 = 0.f, s2 = 0.f;
        int cur = -2;
        for (int n = n0; n < n1; ++n) {
            int bg = sg[n];
            if (bg < 0) continue;
            if (bg != cur) {
                if (cur >= 0) { atomicAdd(&gsum[cur * HID + f], s1); atomicAdd(&gsumsq[cur * HID + f], s2); }
                cur = bg; s1 = 0.f; s2 = 0.f;
            }
            float v = sv[n][f];
            s1 += v; s2 += v * v;
        }
        if (cur >= 0) { atomicAdd(&gsum[cur * HID + f], s1); atomicAdd(&gsumsq[cur * HID + f], s2); }
    }
}

// ---------------- fused GraphNorm (inline coeffs) + relu(+residual) + next features / pool ----
__global__ void norm_feat(const unsigned int* __restrict__ tb,
                          const float* __restrict__ gsum, const float* __restrict__ gsumsq,
                          const float* __restrict__ gcnt, const int* __restrict__ batch,
                          unsigned int* __restrict__ xb, int N, int residual, int isLast,
                          const float* __restrict__ prmL, const float* __restrict__ prmNext,
                          unsigned int* __restrict__ hb, float* __restrict__ as_,
                          float* __restrict__ ad_, float* __restrict__ pooled) {
    __shared__ float sW[256], sa[HID], sd[HID];
    __shared__ float sgw[HID], sgb[HID], sga[HID];
    __shared__ float sv[256][HID + 1];
    __shared__ int sg[256];
    int tid = threadIdx.x;
    if (!isLast) {
        sW[tid] = prmNext[tid];
        if (tid < HID) { sa[tid] = prmNext[256 + tid]; sd[tid] = prmNext[272 + tid]; }
    }
    if (tid < HID) { sgw[tid] = prmL[304 + tid]; sgb[tid] = prmL[320 + tid]; sga[tid] = prmL[336 + tid]; }
    __syncthreads();
    int i = blockIdx.x * 256 + tid;
    float v[HID];
    int g = -1;
    if (i < N) {
        g = batch[i];
        float invc = 1.f / gcnt[g];
        const uint4* tp = (const uint4*)(tb + (i << 3));
        uint4 u0 = tp[0], u1 = tp[1];
        unsigned int us[8] = {u0.x, u0.y, u0.z, u0.w, u1.x, u1.y, u1.z, u1.w};
        float ts[HID];
#pragma unroll
        for (int q = 0; q < 8; ++q) {
            ts[2 * q]     = __uint_as_float(us[q] << 16);
            ts[2 * q + 1] = __uint_as_float(us[q] & 0xFFFF0000u);
        }
        float xs[HID];
        if (residual) {
            const uint4* xp = (const uint4*)(xb + (i << 3));
            uint4 y0 = xp[0], y1 = xp[1];
            unsigned int uy[8] = {y0.x, y0.y, y0.z, y0.w, y1.x, y1.y, y1.z, y1.w};
#pragma unroll
            for (int q = 0; q < 8; ++q) {
                xs[2 * q]     = __uint_as_float(uy[q] << 16);
                xs[2 * q + 1] = __uint_as_float(uy[q] & 0xFFFF0000u);
            }
        } else {
#pragma unroll
            for (int f = 0; f < HID; ++f) xs[f] = 0.f;
        }
        const float4* s1p = (const float4*)(gsum + g * HID);
        const float4* s2p = (const float4*)(gsumsq + g * HID);
        float4 sa4[4], sb4[4];
#pragma unroll
        for (int q = 0; q < 4; ++q) { sa4[q] = s1p[q]; sb4[q] = s2p[q]; }
        float s1v[HID], s2v[HID];
#pragma unroll
        for (int q = 0; q < 4; ++q) {
            s1v[q*4+0] = sa4[q].x; s1v[q*4+1] = sa4[q].y; s1v[q*4+2] = sa4[q].z; s1v[q*4+3] = sa4[q].w;
            s2v[q*4+0] = sb4[q].x; s2v[q*4+1] = sb4[q].y; s2v[q*4+2] = sb4[q].z; s2v[q*4+3] = sb4[q].w;
        }
#pragma unroll
        for (int f = 0; f < HID; ++f) {
            float mean = s1v[f] * invc;
            float msq = s2v[f] * invc;
            float ga = sga[f];
            float var = msq + (ga * ga - 2.f * ga) * mean * mean;
            var = fmaxf(var, 0.f);
            float A = sgw[f] * rsqrtf(var + EPS_GN);
            float B = sgb[f] - A * ga * mean;
            float val = fmaf(A, ts[f], B) + xs[f];
            v[f] = fmaxf(val, 0.f);
        }
    }
    if (isLast) {
        sg[tid] = (i < N) ? g : -1;
#pragma unroll
        for (int f = 0; f < HID; ++f) sv[tid][f] = (i < N) ? v[f] : 0.f;
        __syncthreads();
        if (tid < 64) {
            int f = tid & 15;
            int seg = tid >> 4;
            int n0 = seg * 64, n1 = n0 + 64;
            float s1 = 0.f;
            int cur = -2;
            for (int n = n0; n < n1; ++n) {
                int bg = sg[n];
                if (bg < 0) continue;
                if (bg != cur) { if (cur >= 0) atomicAdd(&pooled[cur * HID + f], s1); cur = bg; s1 = 0.f; }
                s1 += sv[n][f];
            }
            if (cur >= 0) atomicAdd(&pooled[cur * HID + f], s1);
        }
    } else if (i < N) {
        uint4* xp = (uint4*)(xb + (i << 3));
        uint4 y0, y1;
        y0.x = pack2(v[0], v[1]);   y0.y = pack2(v[2], v[3]);
        y0.z = pack2(v[4], v[5]);   y0.w = pack2(v[6], v[7]);
        y1.x = pack2(v[8], v[9]);   y1.y = pack2(v[10], v[11]);
        y1.z = pack2(v[12], v[13]); y1.w = pack2(v[14], v[15]);
        xp[0] = y0; xp[1] = y1;
        float hr[HID];
#pragma unroll
        for (int j = 0; j < HID; ++j) hr[j] = 0.f;
#pragma unroll
        for (int k = 0; k < HID; ++k) {
            float xv = v[k];
#pragma unroll
            for (int j = 0; j < HID; ++j) hr[j] = fmaf(xv, sW[k * HID + j], hr[j]);
        }
        float a1 = 0.f, a2 = 0.f;
#pragma unroll
        for (int j = 0; j < HID; ++j) { a1 = fmaf(hr[j], sa[j], a1); a2 = fmaf(hr[j], sd[j], a2); }
        uint4* hp = (uint4*)(hb + (i << 3));
        uint4 w0, w1;
        w0.x = pack2(hr[0], hr[1]);   w0.y = pack2(hr[2], hr[3]);
        w0.z = pack2(hr[4], hr[5]);   w0.w = pack2(hr[6], hr[7]);
        w1.x = pack2(hr[8], hr[9]);   w1.y = pack2(hr[10], hr[11]);
        w1.z = pack2(hr[12], hr[13]); w1.w = pack2(hr[14], hr[15]);
        hp[0] = w0; hp[1] = w1;
        as_[i] = a1; ad_[i] = a2;
    }
}

// ---------------- final linear ----------------
__global__ void final_lin(const float* __restrict__ pooled, const float* __restrict__ gcnt,
                          const float* __restrict__ prm, const int* __restrict__ flags,
                          void* __restrict__ out) {
    int g = blockIdx.x * blockDim.x + threadIdx.x;
    if (g < NGRAPH) {
        float c = gcnt[g];
        float invc = c > 0.f ? 1.f / c : 0.f;
        float o0 = prm[1440], o1 = prm[1441];
#pragma unroll
        for (int f = 0; f < HID; ++f) {
            float p = pooled[g * HID + f] * invc;
            o0 = fmaf(p, prm[1408 + f * 2 + 0], o0);
            o1 = fmaf(p, prm[1408 + f * 2 + 1], o1);
        }
        if (flags[0]) {
            ((bf16*)out)[g * 2 + 0] = __float2bfloat16(o0);
            ((bf16*)out)[g * 2 + 1] = __float2bfloat16(o1);
        } else {
            ((float*)out)[g * 2 + 0] = o0;
            ((float*)out)[g * 2 + 1] = o1;
        }
    }
}

extern "C" void kernel_launch(void* const* d_in, const int* in_sizes, int n_in,
                              void* d_out, int out_size, void* d_ws, size_t ws_size,
                              hipStream_t stream) {
    const void* x = d_in[0];
    const int* ei = (const int*)d_in[1];
    const int* batch = (const int*)d_in[2];
    int N = in_sizes[2];
    int E = in_sizes[1] / 2;
    int din0 = in_sizes[0] / N;
    int NB = (N + BS - 1) / BS;

    float* ws = (float*)d_ws;
    int* flags = (int*)ws;                          // 16 ints
    float* prm = ws + 16;                           // 2048 floats
    unsigned int* hb = (unsigned int*)(ws + 4096);  // N*8 u32 (bf16 h)
    unsigned int* tb = hb + (size_t)N * 8;          // N*8 u32 (bf16 t)
    unsigned int* xb = tb + (size_t)N * 8;          // N*8 u32 (bf16 xcur)
    float* as_ = (float*)(xb + (size_t)N * 8);      // N
    float* ad_ = as_ + N;                           // N
    int* rowStart = (int*)(ad_ + N);                // N+1
    int* gBase = rowStart + (N + 1);                // NBMAX+1
    int* gCursor = gBase + NBMAX + 1;               // NBMAX
    int* csrSrc = gCursor + NBMAX;                  // E (+pad)
    int* bcnt = csrSrc + E + 64;                    // NBMAX   -- start of single-memset region
    float* gstat = (float*)(bcnt + NBMAX);          // 4 layers * 2 * G*HID
    float* pooled = gstat + 4 * 2 * NGRAPH * HID;   // G*HID
    float* gcnt = pooled + NGRAPH * HID;            // G (written by graph_cnt_k)
    uint2* binned = (uint2*)hb;   // E*8B <= 48MB (hb+tb+xb); all dead until after bucket_sort

    PtrPack pk;
    int n = 0;
    for (int l = 0; l < 4; ++l) {
        int dl = (l == 0) ? din0 : HID;
        int base = l * 352;
        const int offs[7] = {0, 256, 272, 288, 304, 320, 336};
        const int cnts[7] = {dl * HID, HID, HID, HID, HID, HID, HID};
        for (int j = 0; j < 7; ++j) {
            pk.src[n] = d_in[4 + l * 7 + j];
            pk.cnt[n] = cnts[j];
            pk.dstoff[n] = base + offs[j];
            ++n;
        }
    }
    pk.src[n] = d_in[32]; pk.cnt[n] = HID * 2; pk.dstoff[n] = 1408; ++n;
    pk.src[n] = d_in[33]; pk.cnt[n] = 2;       pk.dstoff[n] = 1440; ++n;
    pk.n = n;

    int nbN = (N + 255) / 256;

    detect_cvt<<<1, 256, 0, stream>>>(x, ei, flags, pk, prm);

    // one memset covers bcnt + all per-layer stats + pooled
    size_t zbytes = (size_t)(NBMAX + 4 * 2 * NGRAPH * HID + NGRAPH * HID) * sizeof(int);
    hipMemsetAsync(bcnt, 0, zbytes, stream);

    bucket_count<<<1024, 256, 0, stream>>>(ei, E, flags, bcnt, NB);
    scan_buckets<<<1, 256, 0, stream>>>(bcnt, NB, E, gBase, gCursor, rowStart, N);
    bucket_scatter<<<1024, 256, 0, stream>>>(ei, E, flags, gCursor, binned, NB);
    bucket_sort<<<NB, 1024, 0, stream>>>(binned, gBase, csrSrc, rowStart, N);
    graph_cnt_k<<<(NGRAPH + 255) / 256, 256, 0, stream>>>(batch, N, gcnt);

    node_feat0<<<nbN, 256, 0, stream>>>(x, din0, flags, prm, hb, as_, ad_, N);

    for (int l = 0; l < 4; ++l) {
        const float* prmL = prm + l * 352;
        const float* prmNext = prm + (l + 1 < 4 ? (l + 1) * 352 : 0);
        float* gsumL = gstat + l * 2 * NGRAPH * HID;
        float* gsumsqL = gsumL + NGRAPH * HID;

        gat_agg<<<nbN, 256, 0, stream>>>(rowStart, csrSrc, hb, as_, ad_, prmL, batch,
                                         tb, gsumL, gsumsqL, N);
        norm_feat<<<nbN, 256, 0, stream>>>(tb, gsumL, gsumsqL, gcnt, batch, xb, N,
                                           l > 0 ? 1 : 0, l == 3 ? 1 : 0, prmL, prmNext,
                                           hb, as_, ad_, pooled);
    }

    final_lin<<<(NGRAPH + 255) / 256, 256, 0, stream>>>(pooled, gcnt, prm, flags, d_out);
}

// Round 11
// 1001.535 us; speedup vs baseline: 3.4753x; 1.0032x over previous
//
#include <hip/hip_runtime.h>
#include <hip/hip_bf16.h>

#define HID 16
#define NGRAPH 1000
#define NEG_SLOPE 0.2f
#define EPS_GN 1e-5f
#define BSH 11              // bucket shift: 2048 dsts per bucket (r8 proven; r9/r10's 1024 regressed scatter)
#define BS 2048             // bucket span (power of 2)
#define NBMAX 2048
#define CHK 8192            // edges per scatter chunk (bigger runs -> better write combining)

typedef __hip_bfloat16 bf16;

static __device__ __forceinline__ float b2f(bf16 v) { return __bfloat162float(v); }

// pack two floats into one u32 holding two RNE-rounded bf16s (a=low, b=high)
static __device__ __forceinline__ unsigned int pack2(float a, float b) {
    unsigned int ia = __float_as_uint(a);
    unsigned int ib = __float_as_uint(b);
    ia += 0x7FFFu + ((ia >> 16) & 1u);
    ib += 0x7FFFu + ((ib >> 16) & 1u);
    return (ia >> 16) | (ib & 0xFFFF0000u);
}

// acc[0..15] += p * bf16row(ra,rb)
static __device__ __forceinline__ void fma_row(const uint4 ra, const uint4 rb, float p,
                                               float* __restrict__ acc) {
    unsigned int us[8] = {ra.x, ra.y, ra.z, ra.w, rb.x, rb.y, rb.z, rb.w};
#pragma unroll
    for (int q = 0; q < 8; ++q) {
        float lo = __uint_as_float(us[q] << 16);
        float hi = __uint_as_float(us[q] & 0xFFFF0000u);
        acc[2 * q]     = fmaf(p, lo, acc[2 * q]);
        acc[2 * q + 1] = fmaf(p, hi, acc[2 * q + 1]);
    }
}

struct PtrPack { const void* src[30]; int cnt[30]; int dstoff[30]; int n; };

// ---------------- dtype detection + param conversion (single block) ----------------
__global__ void detect_cvt(const void* x, const void* ei, int* flags, PtrPack pk,
                           float* __restrict__ dst) {
    __shared__ int cbf, czero;
    __shared__ int isbS;
    int t = threadIdx.x;
    if (t == 0) { cbf = 0; czero = 0; }
    __syncthreads();
    const unsigned int* xw = (const unsigned int*)x;
    unsigned int w = xw[t * 4];
    int e_lo = (int)((w >> 7) & 0xFF);
    if (e_lo >= 100 && e_lo <= 140) atomicAdd(&cbf, 1);
    const unsigned int* ew = (const unsigned int*)ei;
    if (ew[2 * t + 1] == 0u) atomicAdd(&czero, 1);
    __syncthreads();
    if (t == 0) {
        int isb = (cbf >= 192) ? 1 : 0;
        flags[0] = isb;
        flags[1] = (czero >= 250) ? 1 : 0;
        isbS = isb;
    }
    __syncthreads();
    int isb = isbS;
    for (int j = 0; j < pk.n; ++j) {
        const void* s = pk.src[j];
        int c = pk.cnt[j], o = pk.dstoff[j];
        for (int i = t; i < c; i += blockDim.x) {
            float v = isb ? b2f(((const bf16*)s)[i]) : ((const float*)s)[i];
            dst[o + i] = v;
        }
    }
}

static __device__ __forceinline__ int ld_src(const int* ei, int E, int e, int i64) {
    return i64 ? ei[2ll * e] : ei[e];
}
static __device__ __forceinline__ int ld_dst(const int* ei, int E, int e, int i64) {
    return i64 ? ei[2ll * (E + e)] : ei[(long long)E + e];
}

// ---------------- CSR build: two-level bucket counting sort (r8-proven shape) ----------------

__global__ void bucket_count(const int* __restrict__ ei, int E, const int* __restrict__ flags,
                             int* __restrict__ bcnt, int NB) {
    __shared__ int lh[NBMAX];
    int tid = threadIdx.x;
    for (int i = tid; i < NB; i += 256) lh[i] = 0;
    __syncthreads();
    int i64 = flags[1];
    int stride = gridDim.x * 256;
    for (int e = blockIdx.x * 256 + tid; e < E; e += stride)
        atomicAdd(&lh[ld_dst(ei, E, e, i64) >> BSH], 1);
    __syncthreads();
    for (int i = tid; i < NB; i += 256)
        if (lh[i]) atomicAdd(&bcnt[i], lh[i]);
}

__global__ void scan_buckets(const int* __restrict__ bcnt, int NB, int E,
                             int* __restrict__ gBase, int* __restrict__ gCursor,
                             int* __restrict__ rowStart, int N) {
    __shared__ int part[256];
    int t = threadIdx.x;
    int per = (NB + 255) >> 8;
    int lo = t * per, hi = min(lo + per, NB);
    int s = 0;
    for (int i = lo; i < hi; ++i) s += bcnt[i];
    part[t] = s;
    __syncthreads();
    for (int off = 1; off < 256; off <<= 1) {
        int v = (t >= off) ? part[t - off] : 0;
        __syncthreads();
        part[t] += v;
        __syncthreads();
    }
    int acc = (t == 0) ? 0 : part[t - 1];
    for (int i = lo; i < hi; ++i) {
        gBase[i] = acc; gCursor[i] = acc;
        acc += bcnt[i];
    }
    if (t == 0) { gBase[NB] = E; rowStart[N] = E; }
}

__global__ void bucket_scatter(const int* __restrict__ ei, int E, const int* __restrict__ flags,
                               int* __restrict__ gCursor, uint2* __restrict__ binned, int NB) {
    __shared__ int lh[NBMAX];
    __shared__ int lbase[NBMAX];
    __shared__ int lcur[NBMAX];
    int tid = threadIdx.x;
    int i64 = flags[1];
    int nchunk = (E + CHK - 1) / CHK;
    for (int chunk = blockIdx.x; chunk < nchunk; chunk += gridDim.x) {
        int c0 = chunk * CHK;
        int c1 = min(c0 + CHK, E);
        for (int i = tid; i < NB; i += 256) lh[i] = 0;
        __syncthreads();
        for (int e = c0 + tid; e < c1; e += 256)
            atomicAdd(&lh[ld_dst(ei, E, e, i64) >> BSH], 1);
        __syncthreads();
        for (int b = tid; b < NB; b += 256) {
            int c = lh[b];
            lbase[b] = c ? atomicAdd(&gCursor[b], c) : 0;
            lcur[b] = 0;
        }
        __syncthreads();
        for (int e = c0 + tid; e < c1; e += 256) {
            int d = ld_dst(ei, E, e, i64);
            int s = ld_src(ei, E, e, i64);
            int b = d >> BSH;
            int off = atomicAdd(&lcur[b], 1);
            binned[lbase[b] + off] = make_uint2((unsigned)s, (unsigned)(d & (BS - 1)));
        }
        __syncthreads();
    }
}

// per-bucket counting sort in LDS -> csrSrc + rowStart (2 dsts per thread)
__global__ void bucket_sort(const uint2* __restrict__ binned, const int* __restrict__ gBase,
                            int* __restrict__ csrSrc, int* __restrict__ rowStart, int N) {
    __shared__ int hist[BS];
    __shared__ int tsum[1024];
    int tid = threadIdx.x;
    int b = blockIdx.x;
    int base = gBase[b];
    int cnt = gBase[b + 1] - base;
    for (int i = tid; i < BS; i += 1024) hist[i] = 0;
    __syncthreads();
    for (int i = tid; i < cnt; i += 1024)
        atomicAdd(&hist[binned[base + i].y], 1);
    __syncthreads();
    int a0 = hist[2 * tid], a1 = hist[2 * tid + 1];
    tsum[tid] = a0 + a1;
    __syncthreads();
    for (int off = 1; off < 1024; off <<= 1) {
        int v = (tid >= off) ? tsum[tid - off] : 0;
        __syncthreads();
        tsum[tid] += v;
        __syncthreads();
    }
    int excl = (tid == 0) ? 0 : tsum[tid - 1];
    int d0 = b * BS + 2 * tid;
    if (d0 < N) rowStart[d0] = base + excl;
    if (d0 + 1 < N) rowStart[d0 + 1] = base + excl + a0;
    __syncthreads();
    hist[2 * tid] = excl;
    hist[2 * tid + 1] = excl + a0;
    __syncthreads();
    for (int i = tid; i < cnt; i += 1024) {
        uint2 pr = binned[base + i];
        int off = atomicAdd(&hist[pr.y], 1);
        csrSrc[base + off] = (int)pr.x;
    }
}

__global__ void graph_cnt_k(const int* __restrict__ batch, int N, float* __restrict__ gcnt) {
    int g = blockIdx.x * blockDim.x + threadIdx.x;
    if (g < NGRAPH) {
        int lo = 0, hi = N;
        while (lo < hi) { int mid = (lo + hi) >> 1; if (batch[mid] < g) lo = mid + 1; else hi = mid; }
        int lb = lo;
        lo = 0; hi = N;
        while (lo < hi) { int mid = (lo + hi) >> 1; if (batch[mid] <= g) lo = mid + 1; else hi = mid; }
        gcnt[g] = (float)(lo - lb);
    }
}

// ---------------- layer-0 node transform (writes bf16-packed h) ----------------
__global__ void node_feat0(const void* __restrict__ xin, int din,
                           const int* __restrict__ flags, const float* __restrict__ prmL,
                           unsigned int* __restrict__ hb, float* __restrict__ as_,
                           float* __restrict__ ad_, int N) {
    __shared__ float sW[256], sa[HID], sd[HID];
    int t = threadIdx.x;
    if (t < din * HID) sW[t] = prmL[t];
    if (t < HID) { sa[t] = prmL[256 + t]; sd[t] = prmL[272 + t]; }
    __syncthreads();
    int i = blockIdx.x * blockDim.x + t;
    if (i >= N) return;
    int isb = flags[0];
    const float* xf = (const float*)xin;
    const bf16* xb16 = (const bf16*)xin;
    float hr[HID];
#pragma unroll
    for (int j = 0; j < HID; ++j) hr[j] = 0.f;
    int base = i * din;
    for (int k = 0; k < din; ++k) {
        float xv = isb ? b2f(xb16[base + k]) : xf[base + k];
#pragma unroll
        for (int j = 0; j < HID; ++j) hr[j] = fmaf(xv, sW[k * HID + j], hr[j]);
    }
    float a1 = 0.f, a2 = 0.f;
#pragma unroll
    for (int j = 0; j < HID; ++j) { a1 = fmaf(hr[j], sa[j], a1); a2 = fmaf(hr[j], sd[j], a2); }
    uint4* hp = (uint4*)(hb + (i << 3));
    uint4 w0, w1;
    w0.x = pack2(hr[0], hr[1]);   w0.y = pack2(hr[2], hr[3]);
    w0.z = pack2(hr[4], hr[5]);   w0.w = pack2(hr[6], hr[7]);
    w1.x = pack2(hr[8], hr[9]);   w1.y = pack2(hr[10], hr[11]);
    w1.z = pack2(hr[12], hr[13]); w1.w = pack2(hr[14], hr[15]);
    hp[0] = w0; hp[1] = w1;
    as_[i] = a1; ad_[i] = a2;
}

// ---------------- GAT aggregation: lane-per-node, chunk-4 + index prefetch, bf16 h/t ----------
// chunk-4 + launch_bounds(256,4): PROVEN sweet spot (r8/r10: 48 VGPR, no spill, ~133us).
// DO NOT raise occupancy bound (r9: (256,8) -> 64-VGPR cap -> acc[] spills -> 5.7x slower).
// DO NOT widen to chunk-8 (r7: >128 VGPR -> spill -> 1.7x slower).
__global__ void __launch_bounds__(256, 4)
gat_agg(const int* __restrict__ rowStart, const int* __restrict__ csrSrc,
        const unsigned int* __restrict__ hb, const float* __restrict__ as_,
        const float* __restrict__ ad_, const float* __restrict__ prmL,
        const int* __restrict__ batch,
        unsigned int* __restrict__ tb, float* __restrict__ gsum,
        float* __restrict__ gsumsq, int N) {
    __shared__ float sv[256][HID + 1];
    __shared__ int sg[256];
    int tid = threadIdx.x;
    int node = blockIdx.x * 256 + tid;
    bool valid = node < N;
    float acc[HID];
    float tv[HID];
    int g = -1;
    if (valid) {
        int start = rowStart[node];
        int end = rowStart[node + 1];
        float adi = ad_[node];
        float zs = as_[node] + adi;
        float e_self = zs > 0.f ? zs : NEG_SLOPE * zs;
        float m = e_self, ssum = 0.f;
#pragma unroll
        for (int f = 0; f < HID; ++f) acc[f] = 0.f;
        int s[4];
        if (start < end) {
            int rem = end - start;
            s[0] = csrSrc[start];
#pragma unroll
            for (int k = 1; k < 4; ++k) s[k] = (k < rem) ? csrSrc[start + k] : s[0];
        }
        for (int base = start; base < end; base += 4) {
            int rem = end - base;
            float a0 = as_[s[0]], a1 = as_[s[1]], a2 = as_[s[2]], a3 = as_[s[3]];
            const uint4* h0 = (const uint4*)(hb + (s[0] << 3));
            const uint4* h1 = (const uint4*)(hb + (s[1] << 3));
            const uint4* h2 = (const uint4*)(hb + (s[2] << 3));
            const uint4* h3 = (const uint4*)(hb + (s[3] << 3));
            uint4 r00 = h0[0], r01 = h0[1];
            uint4 r10 = h1[0], r11 = h1[1];
            uint4 r20 = h2[0], r21 = h2[1];
            uint4 r30 = h3[0], r31 = h3[1];
            int nbase = base + 4;
            if (nbase < end) {
                int nrem = end - nbase;
                int sn0 = csrSrc[nbase];
                s[0] = sn0;
#pragma unroll
                for (int k = 1; k < 4; ++k) s[k] = (k < nrem) ? csrSrc[nbase + k] : sn0;
            }
            float z0 = a0 + adi, z1 = a1 + adi, z2 = a2 + adi, z3 = a3 + adi;
            float e0 = z0 > 0.f ? z0 : NEG_SLOPE * z0;
            float e1 = (1 < rem) ? (z1 > 0.f ? z1 : NEG_SLOPE * z1) : -1e30f;
            float e2 = (2 < rem) ? (z2 > 0.f ? z2 : NEG_SLOPE * z2) : -1e30f;
            float e3 = (3 < rem) ? (z3 > 0.f ? z3 : NEG_SLOPE * z3) : -1e30f;
            float cm = fmaxf(fmaxf(e0, e1), fmaxf(e2, e3));
            if (cm > m) {
                float sc = __expf(m - cm);
                ssum *= sc;
#pragma unroll
                for (int f = 0; f < HID; ++f) acc[f] *= sc;
                m = cm;
            }
            float p0 = __expf(e0 - m);
            float p1 = __expf(e1 - m);
            float p2 = __expf(e2 - m);
            float p3 = __expf(e3 - m);
            ssum += p0 + p1 + p2 + p3;
            fma_row(r00, r01, p0, acc);
            fma_row(r10, r11, p1, acc);
            fma_row(r20, r21, p2, acc);
            fma_row(r30, r31, p3, acc);
        }
        const uint4* hs = (const uint4*)(hb + (node << 3));
        uint4 rs0 = hs[0], rs1 = hs[1];
        float pself = __expf(e_self - m);
        ssum += pself;
        fma_row(rs0, rs1, pself, acc);
        float inv = 1.f / ssum;
#pragma unroll
        for (int f = 0; f < HID; ++f) tv[f] = fmaf(acc[f], inv, prmL[288 + f]);
        uint4* tp = (uint4*)(tb + (node << 3));
        uint4 w0, w1;
        w0.x = pack2(tv[0], tv[1]);   w0.y = pack2(tv[2], tv[3]);
        w0.z = pack2(tv[4], tv[5]);   w0.w = pack2(tv[6], tv[7]);
        w1.x = pack2(tv[8], tv[9]);   w1.y = pack2(tv[10], tv[11]);
        w1.z = pack2(tv[12], tv[13]); w1.w = pack2(tv[14], tv[15]);
        tp[0] = w0; tp[1] = w1;
        g = batch[node];
    }
    sg[tid] = valid ? g : -1;
#pragma unroll
    for (int f = 0; f < HID; ++f) sv[tid][f] = valid ? tv[f] : 0.f;
    __syncthreads();
    if (tid < 64) {
        int f = tid & 15;
        int seg = tid >> 4;
        int n0 = seg * 64, n1 = n0 + 64;
        float s1 = 0.f, s2 = 0.f;
        int cur = -2;
        for (int n = n0; n < n1; ++n) {
            int bg = sg[n];
            if (bg < 0) continue;
            if (bg != cur) {
                if (cur >= 0) { atomicAdd(&gsum[cur * HID + f], s1); atomicAdd(&gsumsq[cur * HID + f], s2); }
                cur = bg; s1 = 0.f; s2 = 0.f;
            }
            float v = sv[n][f];
            s1 += v; s2 += v * v;
        }
        if (cur >= 0) { atomicAdd(&gsum[cur * HID + f], s1); atomicAdd(&gsumsq[cur * HID + f], s2); }
    }
}

// ---------------- fused GraphNorm (inline coeffs) + relu(+residual) + next features / pool ----
__global__ void norm_feat(const unsigned int* __restrict__ tb,
                          const float* __restrict__ gsum, const float* __restrict__ gsumsq,
                          const float* __restrict__ gcnt, const int* __restrict__ batch,
                          unsigned int* __restrict__ xb, int N, int residual, int isLast,
                          const float* __restrict__ prmL, const float* __restrict__ prmNext,
                          unsigned int* __restrict__ hb, float* __restrict__ as_,
                          float* __restrict__ ad_, float* __restrict__ pooled) {
    __shared__ float sW[256], sa[HID], sd[HID];
    __shared__ float sgw[HID], sgb[HID], sga[HID];
    __shared__ float sv[256][HID + 1];
    __shared__ int sg[256];
    int tid = threadIdx.x;
    if (!isLast) {
        sW[tid] = prmNext[tid];
        if (tid < HID) { sa[tid] = prmNext[256 + tid]; sd[tid] = prmNext[272 + tid]; }
    }
    if (tid < HID) { sgw[tid] = prmL[304 + tid]; sgb[tid] = prmL[320 + tid]; sga[tid] = prmL[336 + tid]; }
    __syncthreads();
    int i = blockIdx.x * 256 + tid;
    float v[HID];
    int g = -1;
    if (i < N) {
        g = batch[i];
        float invc = 1.f / gcnt[g];
        const uint4* tp = (const uint4*)(tb + (i << 3));
        uint4 u0 = tp[0], u1 = tp[1];
        unsigned int us[8] = {u0.x, u0.y, u0.z, u0.w, u1.x, u1.y, u1.z, u1.w};
        float ts[HID];
#pragma unroll
        for (int q = 0; q < 8; ++q) {
            ts[2 * q]     = __uint_as_float(us[q] << 16);
            ts[2 * q + 1] = __uint_as_float(us[q] & 0xFFFF0000u);
        }
        float xs[HID];
        if (residual) {
            const uint4* xp = (const uint4*)(xb + (i << 3));
            uint4 y0 = xp[0], y1 = xp[1];
            unsigned int uy[8] = {y0.x, y0.y, y0.z, y0.w, y1.x, y1.y, y1.z, y1.w};
#pragma unroll
            for (int q = 0; q < 8; ++q) {
                xs[2 * q]     = __uint_as_float(uy[q] << 16);
                xs[2 * q + 1] = __uint_as_float(uy[q] & 0xFFFF0000u);
            }
        } else {
#pragma unroll
            for (int f = 0; f < HID; ++f) xs[f] = 0.f;
        }
        const float4* s1p = (const float4*)(gsum + g * HID);
        const float4* s2p = (const float4*)(gsumsq + g * HID);
        float4 sa4[4], sb4[4];
#pragma unroll
        for (int q = 0; q < 4; ++q) { sa4[q] = s1p[q]; sb4[q] = s2p[q]; }
        float s1v[HID], s2v[HID];
#pragma unroll
        for (int q = 0; q < 4; ++q) {
            s1v[q*4+0] = sa4[q].x; s1v[q*4+1] = sa4[q].y; s1v[q*4+2] = sa4[q].z; s1v[q*4+3] = sa4[q].w;
            s2v[q*4+0] = sb4[q].x; s2v[q*4+1] = sb4[q].y; s2v[q*4+2] = sb4[q].z; s2v[q*4+3] = sb4[q].w;
        }
#pragma unroll
        for (int f = 0; f < HID; ++f) {
            float mean = s1v[f] * invc;
            float msq = s2v[f] * invc;
            float ga = sga[f];
            float var = msq + (ga * ga - 2.f * ga) * mean * mean;
            var = fmaxf(var, 0.f);
            float A = sgw[f] * rsqrtf(var + EPS_GN);
            float B = sgb[f] - A * ga * mean;
            float val = fmaf(A, ts[f], B) + xs[f];
            v[f] = fmaxf(val, 0.f);
        }
    }
    if (isLast) {
        sg[tid] = (i < N) ? g : -1;
#pragma unroll
        for (int f = 0; f < HID; ++f) sv[tid][f] = (i < N) ? v[f] : 0.f;
        __syncthreads();
        if (tid < 64) {
            int f = tid & 15;
            int seg = tid >> 4;
            int n0 = seg * 64, n1 = n0 + 64;
            float s1 = 0.f;
            int cur = -2;
            for (int n = n0; n < n1; ++n) {
                int bg = sg[n];
                if (bg < 0) continue;
                if (bg != cur) { if (cur >= 0) atomicAdd(&pooled[cur * HID + f], s1); cur = bg; s1 = 0.f; }
                s1 += sv[n][f];
            }
            if (cur >= 0) atomicAdd(&pooled[cur * HID + f], s1);
        }
    } else if (i < N) {
        uint4* xp = (uint4*)(xb + (i << 3));
        uint4 y0, y1;
        y0.x = pack2(v[0], v[1]);   y0.y = pack2(v[2], v[3]);
        y0.z = pack2(v[4], v[5]);   y0.w = pack2(v[6], v[7]);
        y1.x = pack2(v[8], v[9]);   y1.y = pack2(v[10], v[11]);
        y1.z = pack2(v[12], v[13]); y1.w = pack2(v[14], v[15]);
        xp[0] = y0; xp[1] = y1;
        float hr[HID];
#pragma unroll
        for (int j = 0; j < HID; ++j) hr[j] = 0.f;
#pragma unroll
        for (int k = 0; k < HID; ++k) {
            float xv = v[k];
#pragma unroll
            for (int j = 0; j < HID; ++j) hr[j] = fmaf(xv, sW[k * HID + j], hr[j]);
        }
        float a1 = 0.f, a2 = 0.f;
#pragma unroll
        for (int j = 0; j < HID; ++j) { a1 = fmaf(hr[j], sa[j], a1); a2 = fmaf(hr[j], sd[j], a2); }
        uint4* hp = (uint4*)(hb + (i << 3));
        uint4 w0, w1;
        w0.x = pack2(hr[0], hr[1]);   w0.y = pack2(hr[2], hr[3]);
        w0.z = pack2(hr[4], hr[5]);   w0.w = pack2(hr[6], hr[7]);
        w1.x = pack2(hr[8], hr[9]);   w1.y = pack2(hr[10], hr[11]);
        w1.z = pack2(hr[12], hr[13]); w1.w = pack2(hr[14], hr[15]);
        hp[0] = w0; hp[1] = w1;
        as_[i] = a1; ad_[i] = a2;
    }
}

// ---------------- final linear ----------------
__global__ void final_lin(const float* __restrict__ pooled, const float* __restrict__ gcnt,
                          const float* __restrict__ prm, const int* __restrict__ flags,
                          void* __restrict__ out) {
    int g = blockIdx.x * blockDim.x + threadIdx.x;
    if (g < NGRAPH) {
        float c = gcnt[g];
        float invc = c > 0.f ? 1.f / c : 0.f;
        float o0 = prm[1440], o1 = prm[1441];
#pragma unroll
        for (int f = 0; f < HID; ++f) {
            float p = pooled[g * HID + f] * invc;
            o0 = fmaf(p, prm[1408 + f * 2 + 0], o0);
            o1 = fmaf(p, prm[1408 + f * 2 + 1], o1);
        }
        if (flags[0]) {
            ((bf16*)out)[g * 2 + 0] = __float2bfloat16(o0);
            ((bf16*)out)[g * 2 + 1] = __float2bfloat16(o1);
        } else {
            ((float*)out)[g * 2 + 0] = o0;
            ((float*)out)[g * 2 + 1] = o1;
        }
    }
}

extern "C" void kernel_launch(void* const* d_in, const int* in_sizes, int n_in,
                              void* d_out, int out_size, void* d_ws, size_t ws_size,
                              hipStream_t stream) {
    const void* x = d_in[0];
    const int* ei = (const int*)d_in[1];
    const int* batch = (const int*)d_in[2];
    int N = in_sizes[2];
    int E = in_sizes[1] / 2;
    int din0 = in_sizes[0] / N;
    int NB = (N + BS - 1) / BS;

    float* ws = (float*)d_ws;
    int* flags = (int*)ws;                          // 16 ints
    float* prm = ws + 16;                           // 2048 floats
    unsigned int* hb = (unsigned int*)(ws + 4096);  // N*8 u32 (bf16 h)
    unsigned int* tb = hb + (size_t)N * 8;          // N*8 u32 (bf16 t)
    unsigned int* xb = tb + (size_t)N * 8;          // N*8 u32 (bf16 xcur)
    float* as_ = (float*)(xb + (size_t)N * 8);      // N
    float* ad_ = as_ + N;                           // N
    int* rowStart = (int*)(ad_ + N);                // N+1
    int* gBase = rowStart + (N + 1);                // NBMAX+1
    int* gCursor = gBase + NBMAX + 1;               // NBMAX
    int* csrSrc = gCursor + NBMAX;                  // E (+pad)
    int* bcnt = csrSrc + E + 64;                    // NBMAX   -- start of single-memset region
    float* gstat = (float*)(bcnt + NBMAX);          // 4 layers * 2 * G*HID
    float* pooled = gstat + 4 * 2 * NGRAPH * HID;   // G*HID
    float* gcnt = pooled + NGRAPH * HID;            // G (written by graph_cnt_k)
    uint2* binned = (uint2*)hb;   // E*8B <= 48MB (hb+tb+xb); all dead until after bucket_sort

    PtrPack pk;
    int n = 0;
    for (int l = 0; l < 4; ++l) {
        int dl = (l == 0) ? din0 : HID;
        int base = l * 352;
        const int offs[7] = {0, 256, 272, 288, 304, 320, 336};
        const int cnts[7] = {dl * HID, HID, HID, HID, HID, HID, HID};
        for (int j = 0; j < 7; ++j) {
            pk.src[n] = d_in[4 + l * 7 + j];
            pk.cnt[n] = cnts[j];
            pk.dstoff[n] = base + offs[j];
            ++n;
        }
    }
    pk.src[n] = d_in[32]; pk.cnt[n] = HID * 2; pk.dstoff[n] = 1408; ++n;
    pk.src[n] = d_in[33]; pk.cnt[n] = 2;       pk.dstoff[n] = 1440; ++n;
    pk.n = n;

    int nbN = (N + 255) / 256;
    int nchunk = (E + CHK - 1) / CHK;
    int scatterGrid = nchunk < 1024 ? nchunk : 1024;

    detect_cvt<<<1, 256, 0, stream>>>(x, ei, flags, pk, prm);

    // one memset covers bcnt + all per-layer stats + pooled
    size_t zbytes = (size_t)(NBMAX + 4 * 2 * NGRAPH * HID + NGRAPH * HID) * sizeof(int);
    hipMemsetAsync(bcnt, 0, zbytes, stream);

    bucket_count<<<1024, 256, 0, stream>>>(ei, E, flags, bcnt, NB);
    scan_buckets<<<1, 256, 0, stream>>>(bcnt, NB, E, gBase, gCursor, rowStart, N);
    bucket_scatter<<<scatterGrid, 256, 0, stream>>>(ei, E, flags, gCursor, binned, NB);
    bucket_sort<<<NB, 1024, 0, stream>>>(binned, gBase, csrSrc, rowStart, N);
    graph_cnt_k<<<(NGRAPH + 255) / 256, 256, 0, stream>>>(batch, N, gcnt);

    node_feat0<<<nbN, 256, 0, stream>>>(x, din0, flags, prm, hb, as_, ad_, N);

    for (int l = 0; l < 4; ++l) {
        const float* prmL = prm + l * 352;
        const float* prmNext = prm + (l + 1 < 4 ? (l + 1) * 352 : 0);
        float* gsumL = gstat + l * 2 * NGRAPH * HID;
        float* gsumsqL = gsumL + NGRAPH * HID;

        gat_agg<<<nbN, 256, 0, stream>>>(rowStart, csrSrc, hb, as_, ad_, prmL, batch,
                                         tb, gsumL, gsumsqL, N);
        norm_feat<<<nbN, 256, 0, stream>>>(tb, gsumL, gsumsqL, gcnt, batch, xb, N,
                                           l > 0 ? 1 : 0, l == 3 ? 1 : 0, prmL, prmNext,
                                           hb, as_, ad_, pooled);
    }

    final_lin<<<(NGRAPH + 255) / 256, 256, 0, stream>>>(pooled, gcnt, prm, flags, d_out);
}